// Round 13
// baseline (4515.239 us; speedup 1.0000x reference)
//
#include <hip/hip_runtime.h>
#include <hip/hip_bf16.h>

#define BB 256
#define CC 2048
#define HD 1024
#define TT 64

typedef short bf16x8 __attribute__((ext_vector_type(8)));
typedef float f32x4 __attribute__((ext_vector_type(4)));
typedef int   i32x4 __attribute__((ext_vector_type(4)));

__device__ __forceinline__ float sigmoidf_(float x){ return 1.0f/(1.0f+__expf(-x)); }
__device__ __forceinline__ float tanhf_(float x){ float e=__expf(2.0f*x); return 1.0f - 2.0f/(e+1.0f); }
__device__ __forceinline__ unsigned short bfbits(float x){
  __hip_bfloat16 b = __float2bfloat16(x);
  return *reinterpret_cast<unsigned short*>(&b);
}
__device__ __forceinline__ bf16x8 ldfrag(const __hip_bfloat16* p){
  return *reinterpret_cast<const bf16x8*>(p);
}
// RELEASE: drain stores, write back dirty L2 to the coherence point (no invalidate).
__device__ __forceinline__ void release_wb(){
  asm volatile("s_waitcnt vmcnt(0)\n\tbuffer_wbl2 sc1\n\ts_waitcnt vmcnt(0)" ::: "memory");
}
#define MFMA16(a,b,c) __builtin_amdgcn_mfma_f32_16x16x32_bf16((a),(b),(c),0,0,0)

__global__ void cvt_f32_bf16(const float* __restrict__ in, __hip_bfloat16* __restrict__ out, int n){
  int i = (blockIdx.x*blockDim.x + threadIdx.x)*4;
  int stride = gridDim.x*blockDim.x*4;
  for (; i < n; i += stride){
    float4 v = *reinterpret_cast<const float4*>(in + i);
    ushort4 s;
    s.x = bfbits(v.x); s.y = bfbits(v.y); s.z = bfbits(v.z); s.w = bfbits(v.w);
    *reinterpret_cast<ushort4*>(out + i) = s;
  }
}

// W_ih [3H][C] f32 -> wihp[256 blk][16 slot][2048] bf16.
// slot s<12: gate=s>>2, col=blk*4+(s&3) -> row gate*HD+col. slots 12-15 zero.
__global__ void pack_ih(const float* __restrict__ W, __hip_bfloat16* __restrict__ out){
  size_t i = ((size_t)blockIdx.x*256 + threadIdx.x)*8;
  int k = (int)(i & 2047), r = (int)((i>>11) & 15), b = (int)(i>>15);
  __hip_bfloat16* o = out + i;
  if (r < 12){
    const float* s = W + (size_t)((r>>2)*HD + b*4 + (r&3))*CC + k;
#pragma unroll
    for (int e = 0; e < 8; e++) o[e] = __float2bfloat16(s[e]);
  } else {
#pragma unroll
    for (int e = 0; e < 8; e++) o[e] = __float2bfloat16(0.0f);
  }
}
// W_hh [3H][H] -> whhp[256][16][1024] (same slot map, K=1024).
__global__ void pack_hh(const float* __restrict__ W, __hip_bfloat16* __restrict__ out){
  size_t i = ((size_t)blockIdx.x*256 + threadIdx.x)*8;
  int k = (int)(i & 1023), r = (int)((i>>10) & 15), b = (int)(i>>14);
  __hip_bfloat16* o = out + i;
  if (r < 12){
    const float* s = W + (size_t)((r>>2)*HD + b*4 + (r&3))*HD + k;
#pragma unroll
    for (int e = 0; e < 8; e++) o[e] = __float2bfloat16(s[e]);
  } else {
#pragma unroll
    for (int e = 0; e < 8; e++) o[e] = __float2bfloat16(0.0f);
  }
}
// W_out [C][H] -> woutp[256][16][1024]. slot s<8: C-col blk*8+s. 8-15 zero.
__global__ void pack_out(const float* __restrict__ W, __hip_bfloat16* __restrict__ out){
  size_t i = ((size_t)blockIdx.x*256 + threadIdx.x)*8;
  int k = (int)(i & 1023), r = (int)((i>>10) & 15), b = (int)(i>>14);
  __hip_bfloat16* o = out + i;
  if (r < 8){
    const float* s = W + (size_t)(b*8 + r)*HD + k;
#pragma unroll
    for (int e = 0; e < 8; e++) o[e] = __float2bfloat16(s[e]);
  } else {
#pragma unroll
    for (int e = 0; e < 8; e++) o[e] = __float2bfloat16(0.0f);
  }
}

// Persistent GRU, 256 blocks x 1024 threads (16 waves), 1 block/CU.
// All weights in LDS (128KB/block), PANEL layout: for each 32-k window a 1KB
// panel where lane l's 16B B-fragment sits at panel + l*16 (conflict-free
// ds_read_b128 -- R12's pitched layout aliased 16B super-banks, 1.3e8 confl).
// Progressive K-consumption: K chunks are owned by producer blocks (block j
// owns codes cols [8j,+8), h cols [4j,+4)); each wave waits per-chunk on the
// 32 producer flags and computes that K slice immediately -- the global-max
// skew wait of R12 becomes a pipelined stream. Fast path: single all-flags
// check skips per-chunk polls in steady state.
__global__ __launch_bounds__(1024, 4) void gru_persistent(
    const __hip_bfloat16* __restrict__ wihp,   // [256][16][2048]
    const __hip_bfloat16* __restrict__ whhp,   // [256][16][1024]
    const __hip_bfloat16* __restrict__ woutp,  // [256][16][1024]
    const __hip_bfloat16* __restrict__ noise16,// [256][1024]
    const float* __restrict__ bih, const float* __restrict__ bhh,
    const float* __restrict__ bout,
    float* __restrict__ samples,               // [B][T][C]
    float* __restrict__ hiddens,               // [B][T][H]
    __hip_bfloat16* __restrict__ cbufs,        // [T][B][C]
    __hip_bfloat16* __restrict__ hbufs,        // [T+1][B][H]
    unsigned* flagC, unsigned* flagH)
{
  __shared__ __align__(16) char lds[131072];
  char* ldsIh  = lds;            // 64 panels x 1KB
  char* ldsHh  = lds + 65536;    // 32 panels
  char* ldsOut = lds + 98304;    // 32 panels

  const int tid  = threadIdx.x;
  const int lane = tid & 63;
  const int wid  = tid >> 6;      // 0..15 -> M-tile
  const int b    = blockIdx.x;
  const int rl   = lane & 15;
  const int kg   = lane >> 4;
  const int m0   = wid*16;
  const int j0   = b*4;           // owned H-cols
  const int c0   = b*8;           // owned C-cols

  // ---- weights global -> LDS, panel order (once) ----
  for (int c = tid; c < 4096; c += 1024){
    int slot = c & 15, kgg = (c>>4)&3, kwin = c>>6;
    *(i32x4*)(ldsIh + kwin*1024 + (kgg*16+slot)*16) =
      *(const i32x4*)(wihp + (size_t)b*16*2048 + slot*2048 + kwin*32 + kgg*8);
  }
  for (int c = tid; c < 2048; c += 1024){
    int slot = c & 15, kgg = (c>>4)&3, kwin = c>>6;
    *(i32x4*)(ldsHh + kwin*1024 + (kgg*16+slot)*16) =
      *(const i32x4*)(whhp + (size_t)b*16*1024 + slot*1024 + kwin*32 + kgg*8);
  }
  for (int c = tid; c < 2048; c += 1024){
    int slot = c & 15, kgg = (c>>4)&3, kwin = c>>6;
    *(i32x4*)(ldsOut + kwin*1024 + (kgg*16+slot)*16) =
      *(const i32x4*)(woutp + (size_t)b*16*1024 + slot*1024 + kwin*32 + kgg*8);
  }
  __syncthreads();

  // biases (lane-resident)
  const int gsel = (rl < 12) ? (rl >> 2) : 0;
  const int jcol = j0 + (rl & 3);
  const float bi_g = bih[gsel*HD + jcol];
  const float bh_g = bhh[gsel*HD + jcol];
  const float bo   = bout[c0 + (rl & 7)];

  float hp[4] = {0.f, 0.f, 0.f, 0.f};   // h_t[m0+kg*4+q][j0+rl], lanes rl<4

  auto chunkWait = [&](unsigned* flags, int cbase, unsigned gen){
    for (;;){
      unsigned f = __hip_atomic_load(&flags[cbase + (lane & 31)],
                                     __ATOMIC_RELAXED, __HIP_MEMORY_SCOPE_SYSTEM);
      if (__all((int)(f >= gen))) break;
      __builtin_amdgcn_s_sleep(2);
    }
    asm volatile("" ::: "memory");   // no hoisting of dependent loads above poll
  };
  auto allReady = [&](unsigned* flags, unsigned gen)->bool{
    unsigned f0 = __hip_atomic_load(&flags[lane],     __ATOMIC_RELAXED, __HIP_MEMORY_SCOPE_SYSTEM);
    unsigned f1 = __hip_atomic_load(&flags[lane+64],  __ATOMIC_RELAXED, __HIP_MEMORY_SCOPE_SYSTEM);
    unsigned f2 = __hip_atomic_load(&flags[lane+128], __ATOMIC_RELAXED, __HIP_MEMORY_SCOPE_SYSTEM);
    unsigned f3 = __hip_atomic_load(&flags[lane+192], __ATOMIC_RELAXED, __HIP_MEMORY_SCOPE_SYSTEM);
    bool ok = (f0>=gen) && (f1>=gen) && (f2>=gen) && (f3>=gen);
    bool r = __all((int)ok);
    if (r) asm volatile("" ::: "memory");
    return r;
  };
  auto signal = [&](unsigned* flags, unsigned gen){
    __syncthreads();               // drain all waves' stores before writeback
    if (tid == 0){
      release_wb();
      __hip_atomic_store(&flags[b], gen, __ATOMIC_RELAXED, __HIP_MEMORY_SCOPE_SYSTEM);
    }
  };

#pragma unroll 1
  for (int t = 0; t < TT; t++){
    // -------- phase 1: fused logits + gh from h_t (noise at t=0) ----------
    const __hip_bfloat16* hsrc = (t == 0) ? noise16 : (hbufs + (size_t)t*BB*HD);
    const __hip_bfloat16* arow = hsrc + (size_t)(m0 + rl)*HD + kg*8;
    f32x4 accL = {0.f,0.f,0.f,0.f}, accG = {0.f,0.f,0.f,0.f};
    {
      bool rdy = (t == 0) || allReady(flagH, (unsigned)t);
#pragma unroll 1
      for (int ch = 0; ch < 8; ch++){
        if (!rdy) chunkWait(flagH, ch*32, (unsigned)t);
        const int kb = ch*128;
#pragma unroll
        for (int kw = 0; kw < 4; kw++){
          const int k = kb + kw*32;
          bf16x8 a = ldfrag(arow + k);
          accL = MFMA16(a, *(const bf16x8*)(ldsOut + (k>>5)*1024 + lane*16), accL);
          accG = MFMA16(a, *(const bf16x8*)(ldsHh  + (k>>5)*1024 + lane*16), accG);
        }
      }
    }
    if (t == 0) accG = (f32x4){0.f,0.f,0.f,0.f};   // h0 = 0 -> gh = 0

    __hip_bfloat16* cd = cbufs + (size_t)t*BB*CC;
    if (rl < 8){
#pragma unroll
      for (int q = 0; q < 4; q++){
        const int row = m0 + kg*4 + q;
        float sv = sigmoidf_(accL[q] + bo);
        __builtin_nontemporal_store(sv, &samples[(size_t)row*TT*CC + (size_t)t*CC + c0 + rl]);
        cd[(size_t)row*CC + c0 + rl] = __float2bfloat16(sv);
      }
    }
    signal(flagC, (unsigned)(t+1));

    // -------- phase 2: gi from codes_t (progressive) + gate combine -------
    const __hip_bfloat16* crow = cbufs + (size_t)t*BB*CC + (size_t)(m0 + rl)*CC + kg*8;
    f32x4 accI = {0.f,0.f,0.f,0.f};
    {
      bool rdy = allReady(flagC, (unsigned)(t+1));
#pragma unroll 1
      for (int ch = 0; ch < 8; ch++){
        if (!rdy) chunkWait(flagC, ch*32, (unsigned)(t+1));
        const int kb = ch*256;
#pragma unroll
        for (int kw = 0; kw < 8; kw++){
          const int k = kb + kw*32;
          accI = MFMA16(ldfrag(crow + k),
                        *(const bf16x8*)(ldsIh + (k>>5)*1024 + lane*16), accI);
        }
      }
    }

    __hip_bfloat16* hn = hbufs + (size_t)(t+1)*BB*HD;
    const int base = lane & 48;
    const int jj   = rl & 3;
#pragma unroll
    for (int q = 0; q < 4; q++){
      float sI = accI[q] + bi_g;         // gi + b_ih (this lane's gate/col)
      float sH = accG[q] + bh_g;         // gh + b_hh
      float sAll = sI + sH;
      float rs  = __shfl(sAll, base + jj,     64);
      float zs  = __shfl(sAll, base + 4 + jj, 64);
      float giN = __shfl(sI,   base + 8 + jj, 64);
      float ghN = __shfl(sH,   base + 8 + jj, 64);
      if (rl < 4){
        float rv = sigmoidf_(rs);
        float zv = sigmoidf_(zs);
        float nv = tanhf_(giN + rv*ghN);
        float hv = (1.0f - zv)*nv + zv*hp[q];
        hp[q] = hv;
        const int row = m0 + kg*4 + q;
        __builtin_nontemporal_store(hv, &hiddens[(size_t)row*TT*HD + (size_t)t*HD + j0 + rl]);
        hn[(size_t)row*HD + j0 + rl] = __float2bfloat16(hv);
      }
    }
    signal(flagH, (unsigned)(t+1));
  }
}

extern "C" void kernel_launch(void* const* d_in, const int* in_sizes, int n_in,
                              void* d_out, int out_size, void* d_ws, size_t ws_size,
                              hipStream_t stream) {
  const float* noise = (const float*)d_in[0];
  const float* W_ih  = (const float*)d_in[1];
  const float* b_ih  = (const float*)d_in[2];
  const float* W_hh  = (const float*)d_in[3];
  const float* b_hh  = (const float*)d_in[4];
  const float* W_out = (const float*)d_in[5];
  const float* b_out = (const float*)d_in[6];

  float* samples = (float*)d_out;                  // [B][T][C]
  float* hiddens = samples + (size_t)BB*TT*CC;     // [B][T][H]

  char* w = (char*)d_ws;
  unsigned* flagC = (unsigned*)w;              w += 1024;
  unsigned* flagH = (unsigned*)w;              w += 1024;
  __hip_bfloat16* wihp  = (__hip_bfloat16*)w;  w += (size_t)256*16*CC*2;     // 16MB
  __hip_bfloat16* whhp  = (__hip_bfloat16*)w;  w += (size_t)256*16*HD*2;     // 8MB
  __hip_bfloat16* woutp = (__hip_bfloat16*)w;  w += (size_t)256*16*HD*2;     // 8MB
  __hip_bfloat16* noise16=(__hip_bfloat16*)w;  w += (size_t)BB*HD*2;
  __hip_bfloat16* cbufs = (__hip_bfloat16*)w;  w += (size_t)TT*BB*CC*2;      // 64MB
  __hip_bfloat16* hbufs = (__hip_bfloat16*)w;  w += (size_t)(TT+1)*BB*HD*2;  // 34MB

  hipMemsetAsync(flagC, 0, 2048, stream);
  pack_ih <<<4096, 256, 0, stream>>>(W_ih,  wihp);
  pack_hh <<<2048, 256, 0, stream>>>(W_hh,  whhp);
  pack_out<<<2048, 256, 0, stream>>>(W_out, woutp);
  cvt_f32_bf16<<<256, 256, 0, stream>>>(noise, noise16, BB*HD);

  gru_persistent<<<256, 1024, 0, stream>>>(
      wihp, whhp, woutp, noise16, b_ih, b_hh, b_out,
      samples, hiddens, cbufs, hbufs, flagC, flagH);
}